// Round 1
// baseline (8650.595 us; speedup 1.0000x reference)
//
#include <hip/hip_runtime.h>
#include <math.h>

// ---- model constants (fixed problem size) ----
#define Bc   8
#define Sc   512
#define Dc   768
#define Hc   12
#define DHc  64
#define FFc  3072
#define Lc   12

typedef float  floatx4 __attribute__((ext_vector_type(4)));
typedef short  shortx8 __attribute__((ext_vector_type(8)));
typedef short  shortx4 __attribute__((ext_vector_type(4)));
typedef __bf16 bf16x8  __attribute__((ext_vector_type(8)));

__device__ __forceinline__ short f2bf(float f) {
  union { float f; unsigned u; } x; x.f = f;
  unsigned r = x.u + 0x7fffu + ((x.u >> 16) & 1u);   // RNE
  return (short)(r >> 16);
}
__device__ __forceinline__ float bf2f(short s) {
  union { unsigned u; float f; } x; x.u = ((unsigned)(unsigned short)s) << 16;
  return x.f;
}

// ---------------- GEMM ----------------
// C[M,N] = A[M,K] @ W[K,N]  (bf16 MFMA, fp32 accum), tile 128x128xBK64,
// 256 threads = 4 waves in 2x2, each wave 64x64 via 4x4 of 16x16x32 MFMA.
#define BM 128
#define BN 128
#define BKc 64
#define LR 72   // LDS row stride (BK + 8 pad): 2-way bank aliasing only

enum { EP_QKV, EP_SCORES, EP_CTX, EP_BIASRES, EP_GELU };

template<bool ABF, bool BTR, int EP>
__global__ __launch_bounds__(256, 2)
void gemm_k(const void* __restrict__ Ap, long sAz, int lda,
            const float* __restrict__ B0, const float* __restrict__ B1,
            const float* __restrict__ B2, long sBz, int ldb,
            void* __restrict__ Cp,
            const float* __restrict__ bias0, const float* __restrict__ bias1,
            const float* __restrict__ bias2,
            const float* __restrict__ res,
            int M, int Nn, int K, float scale)
{
  __shared__ short sA[BM * LR];
  __shared__ short sB[BN * LR];

  const int tid = threadIdx.x;
  const int z   = blockIdx.z;
  const int m0  = blockIdx.y * BM;
  const int n0  = blockIdx.x * BN;

  const float* Bw;
  const float* bias;
  if (EP == EP_QKV) {
    Bw   = (z == 0) ? B0 : (z == 1 ? B1 : B2);
    bias = (z == 0) ? bias0 : (z == 1 ? bias1 : bias2);
  } else {
    Bw   = B0 + (long)z * sBz;
    bias = bias0;
  }

  floatx4 acc[4][4];
  #pragma unroll
  for (int i = 0; i < 4; ++i)
    #pragma unroll
    for (int j = 0; j < 4; ++j) acc[i][j] = (floatx4)0.f;

  const int wave = tid >> 6, lane = tid & 63;
  const int wm = (wave >> 1) * 64, wn = (wave & 1) * 64;
  const int quad = lane >> 4, r16 = lane & 15;

  const int nkt = K / BKc;
  for (int kt = 0; kt < nkt; ++kt) {
    // ---- stage A tile (BM x BK) into sA[m][k] as bf16 ----
    if (ABF) {
      const short* A = (const short*)Ap + (long)z * sAz + (long)m0 * lda + kt * BKc;
      #pragma unroll
      for (int i = 0; i < 4; ++i) {
        int id = tid + i * 256;
        int r = id >> 3, c = id & 7;
        shortx8 v = *(const shortx8*)(A + (long)r * lda + c * 8);
        *(shortx8*)(sA + r * LR + c * 8) = v;
      }
    } else {
      const float* A = (const float*)Ap + (long)z * sAz + (long)m0 * lda + kt * BKc;
      #pragma unroll
      for (int i = 0; i < 8; ++i) {
        int id = tid + i * 256;
        int r = id >> 4, c = id & 15;
        float4 v = *(const float4*)(A + (long)r * lda + c * 4);
        shortx4 p; p.x = f2bf(v.x); p.y = f2bf(v.y); p.z = f2bf(v.z); p.w = f2bf(v.w);
        *(shortx4*)(sA + r * LR + c * 4) = p;
      }
    }
    // ---- stage B tile into sB[n][k] as bf16 ----
    if (!BTR) {
      // B is [N,K] row-major (e.g. K-matrix in scores): direct
      const float* Bb = Bw + (long)n0 * ldb + kt * BKc;
      #pragma unroll
      for (int i = 0; i < 8; ++i) {
        int id = tid + i * 256;
        int r = id >> 4, c = id & 15;
        float4 v = *(const float4*)(Bb + (long)r * ldb + c * 4);
        shortx4 p; p.x = f2bf(v.x); p.y = f2bf(v.y); p.z = f2bf(v.z); p.w = f2bf(v.w);
        *(shortx4*)(sB + r * LR + c * 4) = p;
      }
    } else {
      // B is [K,N] row-major (weights): transpose while staging
      const float* Bb = Bw + (long)(kt * BKc) * ldb + n0;
      #pragma unroll
      for (int i = 0; i < 8; ++i) {
        int id = tid + i * 256;
        int r = id >> 5, c4 = id & 31;
        int n = n0 + c4 * 4;
        float4 v = make_float4(0.f, 0.f, 0.f, 0.f);
        if (n < Nn) v = *(const float4*)(Bb + (long)r * ldb + c4 * 4);
        sB[(c4 * 4 + 0) * LR + r] = f2bf(v.x);
        sB[(c4 * 4 + 1) * LR + r] = f2bf(v.y);
        sB[(c4 * 4 + 2) * LR + r] = f2bf(v.z);
        sB[(c4 * 4 + 3) * LR + r] = f2bf(v.w);
      }
    }
    __syncthreads();

    // ---- MFMA over the 64-k tile (2 chunks of 32) ----
    #pragma unroll
    for (int kc = 0; kc < 2; ++kc) {
      const int ko = kc * 32 + quad * 8;
      bf16x8 af[4], bv[4];
      #pragma unroll
      for (int mi = 0; mi < 4; ++mi)
        af[mi] = __builtin_bit_cast(bf16x8, *(const shortx8*)(sA + (wm + mi * 16 + r16) * LR + ko));
      #pragma unroll
      for (int ni = 0; ni < 4; ++ni)
        bv[ni] = __builtin_bit_cast(bf16x8, *(const shortx8*)(sB + (wn + ni * 16 + r16) * LR + ko));
      #pragma unroll
      for (int mi = 0; mi < 4; ++mi)
        #pragma unroll
        for (int ni = 0; ni < 4; ++ni)
          acc[mi][ni] = __builtin_amdgcn_mfma_f32_16x16x32_bf16(af[mi], bv[ni], acc[mi][ni], 0, 0, 0);
    }
    __syncthreads();
  }

  // ---- epilogue: C/D layout col=lane&15, row=quad*4+reg ----
  #pragma unroll
  for (int mi = 0; mi < 4; ++mi) {
    #pragma unroll
    for (int ni = 0; ni < 4; ++ni) {
      #pragma unroll
      for (int r = 0; r < 4; ++r) {
        int mm = m0 + wm + mi * 16 + quad * 4 + r;
        int nn = n0 + wn + ni * 16 + r16;
        if (nn >= Nn) continue;
        float v = acc[mi][ni][r];
        if (EP == EP_SCORES) {
          ((short*)Cp)[(long)z * (Sc * Sc) + (long)mm * Sc + nn] = f2bf(v * scale);
        } else if (EP == EP_QKV) {
          v += bias[nn];
          int b = mm >> 9, s = mm & 511;
          int hh = nn >> 6, dd = nn & 63;
          ((float*)Cp)[((((long)z * Bc + b) * Hc + hh) * Sc + s) * DHc + dd] = v;
        } else if (EP == EP_CTX) {
          int b = z / Hc, hh = z % Hc;
          ((float*)Cp)[((long)b * Sc + mm) * Dc + hh * DHc + nn] = v;
        } else if (EP == EP_BIASRES) {
          long idx = (long)mm * Dc + nn;
          ((float*)Cp)[idx] = v + bias[nn] + res[idx];
        } else if (EP == EP_GELU) {
          v += bias[nn];
          float g = 0.5f * v * (1.f + erff(v * 0.70710678118654752f));
          ((short*)Cp)[(long)mm * FFc + nn] = f2bf(g);
        }
      }
    }
  }
}

// ---------------- reductions / LN ----------------
__device__ __forceinline__ void block_red2(float& s, float& ss) {
  #pragma unroll
  for (int off = 32; off; off >>= 1) {
    s  += __shfl_xor(s, off);
    ss += __shfl_xor(ss, off);
  }
  __shared__ float rs[4], rss[4];
  int wave = threadIdx.x >> 6, lane = threadIdx.x & 63;
  __syncthreads();
  if (lane == 0) { rs[wave] = s; rss[wave] = ss; }
  __syncthreads();
  s  = rs[0] + rs[1] + rs[2] + rs[3];
  ss = rss[0] + rss[1] + rss[2] + rss[3];
}

__device__ __forceinline__ void ln3(float a0, float a1, float a2,
                                    const float* __restrict__ g,
                                    const float* __restrict__ bb,
                                    float* __restrict__ out, int tid) {
  float s = a0 + a1 + a2;
  float ss = a0 * a0 + a1 * a1 + a2 * a2;
  block_red2(s, ss);
  float mu  = s * (1.f / 768.f);
  float var = ss * (1.f / 768.f) - mu * mu;
  float rstd = rsqrtf(var + 1e-12f);
  out[tid]       = (a0 - mu) * rstd * g[tid]       + bb[tid];
  out[tid + 256] = (a1 - mu) * rstd * g[tid + 256] + bb[tid + 256];
  out[tid + 512] = (a2 - mu) * rstd * g[tid + 512] + bb[tid + 512];
}

__global__ __launch_bounds__(256)
void embed_k(const int* __restrict__ ids, const float* __restrict__ we,
             const float* __restrict__ pe, const float* __restrict__ te,
             const float* __restrict__ g, const float* __restrict__ bb,
             float* __restrict__ y) {
  int row = blockIdx.x, tid = threadIdx.x;
  int s = row & 511;
  long wo = (long)ids[row] * Dc;
  long po = (long)s * Dc;
  float a0 = we[wo + tid]       + pe[po + tid]       + te[tid];
  float a1 = we[wo + tid + 256] + pe[po + tid + 256] + te[tid + 256];
  float a2 = we[wo + tid + 512] + pe[po + tid + 512] + te[tid + 512];
  ln3(a0, a1, a2, g, bb, y + (long)row * Dc, tid);
}

__global__ __launch_bounds__(256)
void ln_k(const float* __restrict__ x, const float* __restrict__ g,
          const float* __restrict__ bb, float* __restrict__ y) {
  long base = (long)blockIdx.x * Dc;
  int tid = threadIdx.x;
  float a0 = x[base + tid], a1 = x[base + tid + 256], a2 = x[base + tid + 512];
  ln3(a0, a1, a2, g, bb, y + base, tid);
}

// in-place masked softmax on bf16 scores; one wave per 512-row
__global__ __launch_bounds__(256)
void softmax_k(short* __restrict__ sc, const int* __restrict__ msk) {
  int wave = threadIdx.x >> 6, lane = threadIdx.x & 63;
  long row = (long)blockIdx.x * 4 + wave;
  short* sr = sc + row * Sc;
  float v[8]; float mx = -1e30f;
  #pragma unroll
  for (int i = 0; i < 8; ++i) { v[i] = bf2f(sr[i * 64 + lane]); mx = fmaxf(mx, v[i]); }
  #pragma unroll
  for (int off = 32; off; off >>= 1) mx = fmaxf(mx, __shfl_xor(mx, off));
  float s = 0.f;
  #pragma unroll
  for (int i = 0; i < 8; ++i) { v[i] = __expf(v[i] - mx); s += v[i]; }
  #pragma unroll
  for (int off = 32; off; off >>= 1) s += __shfl_xor(s, off);
  float inv = 1.f / s;
  int b = (int)(row / (Hc * Sc));
  const int* mr = msk + b * Sc;
  float s2 = 0.f;
  #pragma unroll
  for (int i = 0; i < 8; ++i) { v[i] *= inv * (float)mr[i * 64 + lane]; s2 += v[i]; }
  #pragma unroll
  for (int off = 32; off; off >>= 1) s2 += __shfl_xor(s2, off);
  float r2 = 1.f / fmaxf(s2, 1e-9f);
  #pragma unroll
  for (int i = 0; i < 8; ++i) sr[i * 64 + lane] = f2bf(v[i] * r2);
}

// mean-pool over S with mask, then L2-normalize; one block per batch
__global__ __launch_bounds__(256)
void pool_k(const float* __restrict__ h, const int* __restrict__ msk,
            float* __restrict__ out) {
  int b = blockIdx.x, tid = threadIdx.x;
  float cnt = 0.f, d0 = 0.f;
  for (int s = tid; s < Sc; s += 256) cnt += (float)msk[b * Sc + s];
  block_red2(cnt, d0);
  float a0 = 0.f, a1 = 0.f, a2 = 0.f;
  const float* hb = h + (long)b * Sc * Dc;
  for (int s = 0; s < Sc; ++s) {
    float mk = (float)msk[b * Sc + s];
    if (mk != 0.f) {
      const float* hr = hb + (long)s * Dc;
      a0 += hr[tid] * mk; a1 += hr[tid + 256] * mk; a2 += hr[tid + 512] * mk;
    }
  }
  float dn = 1.f / fmaxf(cnt, 1e-6f);
  a0 *= dn; a1 *= dn; a2 *= dn;
  float ssq = a0 * a0 + a1 * a1 + a2 * a2, d1 = 0.f;
  block_red2(ssq, d1);
  float rn = 1.f / fmaxf(sqrtf(ssq), 1e-12f);
  out[b * Dc + tid]       = a0 * rn;
  out[b * Dc + tid + 256] = a1 * rn;
  out[b * Dc + tid + 512] = a2 * rn;
}

// ---------------- launcher ----------------
extern "C" void kernel_launch(void* const* d_in, const int* in_sizes, int n_in,
                              void* d_out, int out_size, void* d_ws, size_t ws_size,
                              hipStream_t stream)
{
  const int*   ids   = (const int*)d_in[0];
  const int*   amask = (const int*)d_in[1];
  const float* we    = (const float*)d_in[2];
  const float* pe    = (const float*)d_in[3];
  const float* te    = (const float*)d_in[4];
  const float* elg   = (const float*)d_in[5];
  const float* elb   = (const float*)d_in[6];
  const float* Wq    = (const float*)d_in[7];
  const float* bq    = (const float*)d_in[8];
  const float* Wk    = (const float*)d_in[9];
  const float* bk    = (const float*)d_in[10];
  const float* Wv    = (const float*)d_in[11];
  const float* bv    = (const float*)d_in[12];
  const float* Wo    = (const float*)d_in[13];
  const float* bo    = (const float*)d_in[14];
  const float* l1g   = (const float*)d_in[15];
  const float* l1b   = (const float*)d_in[16];
  const float* Wi    = (const float*)d_in[17];
  const float* bi    = (const float*)d_in[18];
  const float* Wf    = (const float*)d_in[19];
  const float* bfp   = (const float*)d_in[20];
  const float* l2g   = (const float*)d_in[21];
  const float* l2b   = (const float*)d_in[22];
  float* out = (float*)d_out;

  const long HD = (long)Bc * Sc * Dc;        // 3,145,728
  const long SS = (long)Bc * Hc * Sc * Sc;   // 25,165,824
  float* ws    = (float*)d_ws;
  float* h     = ws;            // HD
  float* q     = ws + 1 * HD;   // [B,H,S,DH]
  float* kk    = ws + 2 * HD;
  float* vvb   = ws + 3 * HD;
  float* ctx   = ws + 4 * HD;   // [B,S,D]
  float* t1    = ws + 5 * HD;   // pre-LN temp (attn and ff reuse)
  float* attn  = ws + 6 * HD;   // post-LN1
  short* scoresb = (short*)(ws + 7 * HD);       // SS bf16 (softmax in-place -> probs)
  short* inter   = (short*)(ws + 7 * HD + SS / 2);  // B*S*FF bf16

  embed_k<<<Bc * Sc, 256, 0, stream>>>(ids, we, pe, te, elg, elb, h);

  for (int l = 0; l < Lc; ++l) {
    const float* wq = Wq + (long)l * Dc * Dc;
    const float* wk = Wk + (long)l * Dc * Dc;
    const float* wv = Wv + (long)l * Dc * Dc;
    const float* wo = Wo + (long)l * Dc * Dc;
    const float* wi = Wi + (long)l * Dc * FFc;
    const float* wf = Wf + (long)l * FFc * Dc;

    // QKV: one launch, z selects W/bias; out [3][B,H,S,DH]
    gemm_k<false, true, EP_QKV><<<dim3(6, 32, 3), 256, 0, stream>>>(
        h, 0, Dc, wq, wk, wv, 0, Dc, q,
        bq + l * Dc, bk + l * Dc, bv + l * Dc, nullptr,
        Bc * Sc, Dc, Dc, 1.f);

    // scores = q k^T / 8 -> bf16, batched over 96 (b,h)
    gemm_k<false, false, EP_SCORES><<<dim3(4, 4, 96), 256, 0, stream>>>(
        q, (long)Sc * DHc, DHc, kk, nullptr, nullptr, (long)Sc * DHc, DHc,
        scoresb, nullptr, nullptr, nullptr, nullptr,
        Sc, Sc, DHc, 0.125f);

    softmax_k<<<(Bc * Hc * Sc) / 4, 256, 0, stream>>>(scoresb, amask);

    // ctx = probs @ v  -> [B,S,D]
    gemm_k<true, true, EP_CTX><<<dim3(1, 4, 96), 256, 0, stream>>>(
        scoresb, (long)Sc * Sc, Sc, vvb, nullptr, nullptr, (long)Sc * DHc, DHc,
        ctx, nullptr, nullptr, nullptr, nullptr,
        Sc, DHc, Sc, 1.f);

    // attn pre-LN = ctx @ Wo + bo + h
    gemm_k<false, true, EP_BIASRES><<<dim3(6, 32, 1), 256, 0, stream>>>(
        ctx, 0, Dc, wo, nullptr, nullptr, 0, Dc,
        t1, bo + l * Dc, nullptr, nullptr, h,
        Bc * Sc, Dc, Dc, 1.f);

    ln_k<<<Bc * Sc, 256, 0, stream>>>(t1, l1g + l * Dc, l1b + l * Dc, attn);

    // inter = gelu(attn @ Wi + bi) -> bf16
    gemm_k<false, true, EP_GELU><<<dim3(24, 32, 1), 256, 0, stream>>>(
        attn, 0, Dc, wi, nullptr, nullptr, 0, FFc,
        inter, bi + l * FFc, nullptr, nullptr, nullptr,
        Bc * Sc, FFc, Dc, 1.f);

    // ff pre-LN = inter @ Wf + bf + attn
    gemm_k<true, true, EP_BIASRES><<<dim3(6, 32, 1), 256, 0, stream>>>(
        inter, 0, FFc, wf, nullptr, nullptr, 0, Dc,
        t1, bfp + l * Dc, nullptr, nullptr, attn,
        Bc * Sc, Dc, FFc, 1.f);

    ln_k<<<Bc * Sc, 256, 0, stream>>>(t1, l2g + l * Dc, l2b + l * Dc, h);
  }

  pool_k<<<Bc, 256, 0, stream>>>(h, amask, out);
}

// Round 2
// 6715.308 us; speedup vs baseline: 1.2882x; 1.2882x over previous
//
#include <hip/hip_runtime.h>
#include <math.h>

// ---- model constants (fixed problem size) ----
#define Bc   8
#define Sc   512
#define Dc   768
#define Hc   12
#define DHc  64
#define FFc  3072
#define Lc   12

typedef float  floatx4 __attribute__((ext_vector_type(4)));
typedef short  shortx8 __attribute__((ext_vector_type(8)));
typedef short  shortx4 __attribute__((ext_vector_type(4)));
typedef __bf16 bf16x8  __attribute__((ext_vector_type(8)));

__device__ __forceinline__ short f2bf(float f) {
  union { float f; unsigned u; } x; x.f = f;
  unsigned r = x.u + 0x7fffu + ((x.u >> 16) & 1u);   // RNE
  return (short)(r >> 16);
}

// ---------------- dense GEMM ----------------
// C[M,N] = A[M,K] @ W[K,N]  (bf16 MFMA, fp32 accum), tile 128x128xBK64,
// 256 threads = 4 waves in 2x2, each wave 64x64 via 4x4 of 16x16x32 MFMA.
#define BM 128
#define BN 128
#define BKc 64
#define LR 72   // LDS row stride (BK + 8 pad)

enum { EP_QKV, EP_BIASRES, EP_GELU };

template<bool ABF, int EP>
__global__ __launch_bounds__(256, 2)
void gemm_k(const void* __restrict__ Ap, int lda,
            const float* __restrict__ B0, const float* __restrict__ B1,
            const float* __restrict__ B2, int ldb,
            void* __restrict__ Cp,
            const float* __restrict__ bias0, const float* __restrict__ bias1,
            const float* __restrict__ bias2,
            const float* __restrict__ res,
            int M, int Nn, int K)
{
  __shared__ short sA[BM * LR];
  __shared__ short sB[BN * LR];

  const int tid = threadIdx.x;
  const int z   = blockIdx.z;
  const int m0  = blockIdx.y * BM;
  const int n0  = blockIdx.x * BN;

  const float* Bw;
  const float* bias;
  if (EP == EP_QKV) {
    Bw   = (z == 0) ? B0 : (z == 1 ? B1 : B2);
    bias = (z == 0) ? bias0 : (z == 1 ? bias1 : bias2);
  } else {
    Bw   = B0;
    bias = bias0;
  }

  floatx4 acc[4][4];
  #pragma unroll
  for (int i = 0; i < 4; ++i)
    #pragma unroll
    for (int j = 0; j < 4; ++j) acc[i][j] = (floatx4)0.f;

  const int wave = tid >> 6, lane = tid & 63;
  const int wm = (wave >> 1) * 64, wn = (wave & 1) * 64;
  const int quad = lane >> 4, r16 = lane & 15;

  const int nkt = K / BKc;
  for (int kt = 0; kt < nkt; ++kt) {
    // ---- stage A tile (BM x BK) into sA[m][k] as bf16 ----
    if (ABF) {
      const short* A = (const short*)Ap + (long)m0 * lda + kt * BKc;
      #pragma unroll
      for (int i = 0; i < 4; ++i) {
        int id = tid + i * 256;
        int r = id >> 3, c = (id & 7) * 8;
        *(shortx8*)(sA + r * LR + c) = *(const shortx8*)(A + (long)r * lda + c);
      }
    } else {
      const float* A = (const float*)Ap + (long)m0 * lda + kt * BKc;
      #pragma unroll
      for (int i = 0; i < 8; ++i) {
        int id = tid + i * 256;
        int r = id >> 4, c = (id & 15) * 4;
        float4 v = *(const float4*)(A + (long)r * lda + c);
        shortx4 p; p.x = f2bf(v.x); p.y = f2bf(v.y); p.z = f2bf(v.z); p.w = f2bf(v.w);
        *(shortx4*)(sA + r * LR + c) = p;
      }
    }
    // ---- stage B tile [K,N] -> sB[n][k] (transpose) ----
    {
      const float* Bb = Bw + (long)(kt * BKc) * ldb + n0;
      #pragma unroll
      for (int i = 0; i < 8; ++i) {
        int id = tid + i * 256;
        int r = id >> 5, c4 = id & 31;
        float4 v = *(const float4*)(Bb + (long)r * ldb + c4 * 4);
        sB[(c4 * 4 + 0) * LR + r] = f2bf(v.x);
        sB[(c4 * 4 + 1) * LR + r] = f2bf(v.y);
        sB[(c4 * 4 + 2) * LR + r] = f2bf(v.z);
        sB[(c4 * 4 + 3) * LR + r] = f2bf(v.w);
      }
    }
    __syncthreads();

    #pragma unroll
    for (int kc = 0; kc < 2; ++kc) {
      const int ko = kc * 32 + quad * 8;
      bf16x8 af[4], bv[4];
      #pragma unroll
      for (int mi = 0; mi < 4; ++mi)
        af[mi] = __builtin_bit_cast(bf16x8, *(const shortx8*)(sA + (wm + mi * 16 + r16) * LR + ko));
      #pragma unroll
      for (int ni = 0; ni < 4; ++ni)
        bv[ni] = __builtin_bit_cast(bf16x8, *(const shortx8*)(sB + (wn + ni * 16 + r16) * LR + ko));
      #pragma unroll
      for (int mi = 0; mi < 4; ++mi)
        #pragma unroll
        for (int ni = 0; ni < 4; ++ni)
          acc[mi][ni] = __builtin_amdgcn_mfma_f32_16x16x32_bf16(af[mi], bv[ni], acc[mi][ni], 0, 0, 0);
    }
    __syncthreads();
  }

  // ---- epilogue: C/D layout col=lane&15, row=quad*4+reg ----
  #pragma unroll
  for (int mi = 0; mi < 4; ++mi) {
    #pragma unroll
    for (int ni = 0; ni < 4; ++ni) {
      #pragma unroll
      for (int r = 0; r < 4; ++r) {
        int mm = m0 + wm + mi * 16 + quad * 4 + r;
        int nn = n0 + wn + ni * 16 + r16;
        float v = acc[mi][ni][r];
        if (EP == EP_QKV) {
          v += bias[nn];
          int b = mm >> 9, s = mm & 511;
          int hh = nn >> 6, dd = nn & 63;
          ((short*)Cp)[((((long)z * Bc + b) * Hc + hh) * Sc + s) * DHc + dd] = f2bf(v);
        } else if (EP == EP_BIASRES) {
          long idx = (long)mm * Dc + nn;
          ((float*)Cp)[idx] = v + bias[nn] + res[idx];
        } else if (EP == EP_GELU) {
          v += bias[nn];
          float g = 0.5f * v * (1.f + erff(v * 0.70710678118654752f));
          ((short*)Cp)[(long)mm * FFc + nn] = f2bf(g);
        }
      }
    }
  }
}

// ---------------- fused flash attention ----------------
// Grid (qt=4, bh=96). Block = 4 waves; wave w owns q-rows w*32..w*32+31.
// Per kt (8 steps of 64 keys): S=Q@K^T -> online softmax (mask folded into p,
// equivalent to ref softmax->mask->renorm since Z cancels) -> P via LDS -> O+=P@V.
#define HDL ((long)Bc * Hc * Sc * DHc)

__global__ __launch_bounds__(256, 2)
void attn_k(const short* __restrict__ qkv, const int* __restrict__ msk,
            short* __restrict__ ctx)
{
  __shared__ short sQ[128 * 72];
  __shared__ short sK[64 * 72];
  __shared__ short sV[64 * 72];   // transposed [dh][kn], kn rotated by 8*((dh+(dh>>3))&7)
  __shared__ short sP[128 * 72];

  const int tid = threadIdx.x;
  const int qt = blockIdx.x, bh = blockIdx.y;
  const int b = bh / Hc, hh = bh % Hc;
  const int wave = tid >> 6, lane = tid & 63;
  const int quad = lane >> 4, r16 = lane & 15;

  const short* Qg = qkv + ((long)bh * Sc + qt * 128) * DHc;
  const short* Kg = qkv + HDL + (long)bh * Sc * DHc;
  const short* Vg = qkv + 2 * HDL + (long)bh * Sc * DHc;

  // stage Q tile (128 x 64)
  #pragma unroll
  for (int i = 0; i < 4; ++i) {
    int id = tid + i * 256;
    int r = id >> 3, c = (id & 7) * 8;
    *(shortx8*)(sQ + r * 72 + c) = *(const shortx8*)(Qg + r * 64 + c);
  }

  floatx4 o[2][4];
  float m_old[2][4], l[2][4];
  #pragma unroll
  for (int mi = 0; mi < 2; ++mi) {
    #pragma unroll
    for (int nj = 0; nj < 4; ++nj) o[mi][nj] = (floatx4)0.f;
    #pragma unroll
    for (int r = 0; r < 4; ++r) { m_old[mi][r] = -3.0e38f; l[mi][r] = 0.f; }
  }

  for (int kt = 0; kt < 8; ++kt) {
    __syncthreads();   // prior-iter LDS reads done (also publishes Q on kt=0)
    // stage K tile (64 x 64)
    #pragma unroll
    for (int i = 0; i < 2; ++i) {
      int id = tid + i * 256;
      int r = id >> 3, c = (id & 7) * 8;
      *(shortx8*)(sK + r * 72 + c) = *(const shortx8*)(Kg + (kt * 64 + r) * 64 + c);
    }
    // stage V tile transposed: sV[dh][kn'], kn' = (kn + 8*((j+c8)&7)) & 63
    #pragma unroll
    for (int i = 0; i < 2; ++i) {
      int id = tid + i * 256;
      int r = id >> 3, c8 = id & 7;
      shortx8 v = *(const shortx8*)(Vg + (kt * 64 + r) * 64 + c8 * 8);
      #pragma unroll
      for (int j = 0; j < 8; ++j) {
        int kn2 = (r + 8 * ((j + c8) & 7)) & 63;
        sV[(c8 * 8 + j) * 72 + kn2] = v[j];
      }
    }
    __syncthreads();

    // ---- S = Q @ K^T (wave: 32 q-rows x 64 keys) ----
    floatx4 s[2][4];
    #pragma unroll
    for (int mi = 0; mi < 2; ++mi)
      #pragma unroll
      for (int ni = 0; ni < 4; ++ni) s[mi][ni] = (floatx4)0.f;
    #pragma unroll
    for (int kc = 0; kc < 2; ++kc) {
      const int ko = kc * 32 + quad * 8;
      bf16x8 aq[2], bk[4];
      #pragma unroll
      for (int mi = 0; mi < 2; ++mi)
        aq[mi] = __builtin_bit_cast(bf16x8, *(const shortx8*)(sQ + (wave * 32 + mi * 16 + r16) * 72 + ko));
      #pragma unroll
      for (int ni = 0; ni < 4; ++ni)
        bk[ni] = __builtin_bit_cast(bf16x8, *(const shortx8*)(sK + (ni * 16 + r16) * 72 + ko));
      #pragma unroll
      for (int mi = 0; mi < 2; ++mi)
        #pragma unroll
        for (int ni = 0; ni < 4; ++ni)
          s[mi][ni] = __builtin_amdgcn_mfma_f32_16x16x32_bf16(aq[mi], bk[ni], s[mi][ni], 0, 0, 0);
    }

    // key mask for this lane's 4 columns
    float mv[4];
    #pragma unroll
    for (int ni = 0; ni < 4; ++ni)
      mv[ni] = (float)msk[b * Sc + kt * 64 + ni * 16 + r16];

    // ---- online softmax (rows = quad*4+r within each 16-tile) ----
    #pragma unroll
    for (int mi = 0; mi < 2; ++mi) {
      #pragma unroll
      for (int r = 0; r < 4; ++r) {
        float mx = fmaxf(fmaxf(s[mi][0][r], s[mi][1][r]), fmaxf(s[mi][2][r], s[mi][3][r]));
        mx *= 0.125f;
        #pragma unroll
        for (int off = 1; off <= 8; off <<= 1) mx = fmaxf(mx, __shfl_xor(mx, off));
        float mn = fmaxf(m_old[mi][r], mx);
        float al = __expf(m_old[mi][r] - mn);
        m_old[mi][r] = mn;
        float rs = 0.f;
        #pragma unroll
        for (int ni = 0; ni < 4; ++ni) {
          float p = __expf(fmaf(s[mi][ni][r], 0.125f, -mn)) * mv[ni];
          s[mi][ni][r] = p;
          rs += p;
        }
        #pragma unroll
        for (int off = 1; off <= 8; off <<= 1) rs += __shfl_xor(rs, off);
        l[mi][r] = l[mi][r] * al + rs;
        #pragma unroll
        for (int nj = 0; nj < 4; ++nj) o[mi][nj][r] *= al;
        int row = wave * 32 + mi * 16 + quad * 4 + r;
        #pragma unroll
        for (int ni = 0; ni < 4; ++ni)
          sP[row * 72 + ni * 16 + r16] = f2bf(s[mi][ni][r]);
      }
    }
    __syncthreads();   // P visible

    // ---- O += P @ V ----
    #pragma unroll
    for (int kc = 0; kc < 2; ++kc) {
      const int ko = kc * 32 + quad * 8;
      bf16x8 ap[2], bv[4];
      #pragma unroll
      for (int mi = 0; mi < 2; ++mi)
        ap[mi] = __builtin_bit_cast(bf16x8, *(const shortx8*)(sP + (wave * 32 + mi * 16 + r16) * 72 + ko));
      #pragma unroll
      for (int nj = 0; nj < 4; ++nj) {
        int dh = nj * 16 + r16;
        int f = (dh + (dh >> 3)) & 7;
        int base = (ko + 8 * f) & 63;
        bv[nj] = __builtin_bit_cast(bf16x8, *(const shortx8*)(sV + dh * 72 + base));
      }
      #pragma unroll
      for (int mi = 0; mi < 2; ++mi)
        #pragma unroll
        for (int nj = 0; nj < 4; ++nj)
          o[mi][nj] = __builtin_amdgcn_mfma_f32_16x16x32_bf16(ap[mi], bv[nj], o[mi][nj], 0, 0, 0);
    }
  }

  // ---- epilogue: ctx[b, s, hh*64+dh] = O / max(l, eps), bf16 ----
  #pragma unroll
  for (int mi = 0; mi < 2; ++mi) {
    #pragma unroll
    for (int r = 0; r < 4; ++r) {
      float inv = 1.f / fmaxf(l[mi][r], 1e-20f);
      int row = qt * 128 + wave * 32 + mi * 16 + quad * 4 + r;
      #pragma unroll
      for (int nj = 0; nj < 4; ++nj) {
        int col = hh * 64 + nj * 16 + r16;
        ctx[((long)b * Sc + row) * Dc + col] = f2bf(o[mi][nj][r] * inv);
      }
    }
  }
}

// ---------------- reductions / LN ----------------
__device__ __forceinline__ void block_red2(float& s, float& ss) {
  #pragma unroll
  for (int off = 32; off; off >>= 1) {
    s  += __shfl_xor(s, off);
    ss += __shfl_xor(ss, off);
  }
  __shared__ float rs[4], rss[4];
  int wave = threadIdx.x >> 6, lane = threadIdx.x & 63;
  __syncthreads();
  if (lane == 0) { rs[wave] = s; rss[wave] = ss; }
  __syncthreads();
  s  = rs[0] + rs[1] + rs[2] + rs[3];
  ss = rss[0] + rss[1] + rss[2] + rss[3];
}

__device__ __forceinline__ void ln3(float a0, float a1, float a2,
                                    const float* __restrict__ g,
                                    const float* __restrict__ bb,
                                    float* __restrict__ out, int tid) {
  float s = a0 + a1 + a2;
  float ss = a0 * a0 + a1 * a1 + a2 * a2;
  block_red2(s, ss);
  float mu  = s * (1.f / 768.f);
  float var = ss * (1.f / 768.f) - mu * mu;
  float rstd = rsqrtf(var + 1e-12f);
  out[tid]       = (a0 - mu) * rstd * g[tid]       + bb[tid];
  out[tid + 256] = (a1 - mu) * rstd * g[tid + 256] + bb[tid + 256];
  out[tid + 512] = (a2 - mu) * rstd * g[tid + 512] + bb[tid + 512];
}

__global__ __launch_bounds__(256)
void embed_k(const int* __restrict__ ids, const float* __restrict__ we,
             const float* __restrict__ pe, const float* __restrict__ te,
             const float* __restrict__ g, const float* __restrict__ bb,
             float* __restrict__ y) {
  int row = blockIdx.x, tid = threadIdx.x;
  int s = row & 511;
  long wo = (long)ids[row] * Dc;
  long po = (long)s * Dc;
  float a0 = we[wo + tid]       + pe[po + tid]       + te[tid];
  float a1 = we[wo + tid + 256] + pe[po + tid + 256] + te[tid + 256];
  float a2 = we[wo + tid + 512] + pe[po + tid + 512] + te[tid + 512];
  ln3(a0, a1, a2, g, bb, y + (long)row * Dc, tid);
}

__global__ __launch_bounds__(256)
void ln_k(const float* __restrict__ x, const float* __restrict__ g,
          const float* __restrict__ bb, float* __restrict__ y) {
  long base = (long)blockIdx.x * Dc;
  int tid = threadIdx.x;
  float a0 = x[base + tid], a1 = x[base + tid + 256], a2 = x[base + tid + 512];
  ln3(a0, a1, a2, g, bb, y + base, tid);
}

// mean-pool over S with mask, then L2-normalize; one block per batch
__global__ __launch_bounds__(256)
void pool_k(const float* __restrict__ h, const int* __restrict__ msk,
            float* __restrict__ out) {
  int b = blockIdx.x, tid = threadIdx.x;
  float cnt = 0.f, d0 = 0.f;
  for (int s = tid; s < Sc; s += 256) cnt += (float)msk[b * Sc + s];
  block_red2(cnt, d0);
  float a0 = 0.f, a1 = 0.f, a2 = 0.f;
  const float* hb = h + (long)b * Sc * Dc;
  for (int s = 0; s < Sc; ++s) {
    float mk = (float)msk[b * Sc + s];
    if (mk != 0.f) {
      const float* hr = hb + (long)s * Dc;
      a0 += hr[tid] * mk; a1 += hr[tid + 256] * mk; a2 += hr[tid + 512] * mk;
    }
  }
  float dn = 1.f / fmaxf(cnt, 1e-6f);
  a0 *= dn; a1 *= dn; a2 *= dn;
  float ssq = a0 * a0 + a1 * a1 + a2 * a2, d1 = 0.f;
  block_red2(ssq, d1);
  float rn = 1.f / fmaxf(sqrtf(ssq), 1e-12f);
  out[b * Dc + tid]       = a0 * rn;
  out[b * Dc + tid + 256] = a1 * rn;
  out[b * Dc + tid + 512] = a2 * rn;
}

// ---------------- launcher ----------------
extern "C" void kernel_launch(void* const* d_in, const int* in_sizes, int n_in,
                              void* d_out, int out_size, void* d_ws, size_t ws_size,
                              hipStream_t stream)
{
  const int*   ids   = (const int*)d_in[0];
  const int*   amask = (const int*)d_in[1];
  const float* we    = (const float*)d_in[2];
  const float* pe    = (const float*)d_in[3];
  const float* te    = (const float*)d_in[4];
  const float* elg   = (const float*)d_in[5];
  const float* elb   = (const float*)d_in[6];
  const float* Wq    = (const float*)d_in[7];
  const float* bq    = (const float*)d_in[8];
  const float* Wk    = (const float*)d_in[9];
  const float* bk    = (const float*)d_in[10];
  const float* Wv    = (const float*)d_in[11];
  const float* bv    = (const float*)d_in[12];
  const float* Wo    = (const float*)d_in[13];
  const float* bo    = (const float*)d_in[14];
  const float* l1g   = (const float*)d_in[15];
  const float* l1b   = (const float*)d_in[16];
  const float* Wi    = (const float*)d_in[17];
  const float* bi    = (const float*)d_in[18];
  const float* Wf    = (const float*)d_in[19];
  const float* bfp   = (const float*)d_in[20];
  const float* l2g   = (const float*)d_in[21];
  const float* l2b   = (const float*)d_in[22];
  float* out = (float*)d_out;

  const long HD = (long)Bc * Sc * Dc;        // 3,145,728
  float* ws    = (float*)d_ws;
  float* h     = ws;            // HD f32
  float* t1    = ws + 1 * HD;   // pre-LN temp
  float* attn  = ws + 2 * HD;   // post-LN1
  short* qkvb  = (short*)(ws + 3 * HD);      // [3][B,H,S,DH] bf16
  short* ctxb  = qkvb + 3 * HD;              // [B,S,D] bf16
  short* inter = ctxb + HD;                  // [B,S,FF] bf16

  embed_k<<<Bc * Sc, 256, 0, stream>>>(ids, we, pe, te, elg, elb, h);

  for (int l = 0; l < Lc; ++l) {
    const float* wq = Wq + (long)l * Dc * Dc;
    const float* wk = Wk + (long)l * Dc * Dc;
    const float* wv = Wv + (long)l * Dc * Dc;
    const float* wo = Wo + (long)l * Dc * Dc;
    const float* wi = Wi + (long)l * Dc * FFc;
    const float* wf = Wf + (long)l * FFc * Dc;

    // QKV: one launch, z selects W/bias; out bf16 [3][B,H,S,DH]
    gemm_k<false, EP_QKV><<<dim3(6, 32, 3), 256, 0, stream>>>(
        h, Dc, wq, wk, wv, Dc, qkvb,
        bq + l * Dc, bk + l * Dc, bv + l * Dc, nullptr,
        Bc * Sc, Dc, Dc);

    // fused flash attention -> ctx bf16 [B,S,D]
    attn_k<<<dim3(4, 96), 256, 0, stream>>>(qkvb, amask, ctxb);

    // attn pre-LN = ctx @ Wo + bo + h
    gemm_k<true, EP_BIASRES><<<dim3(6, 32, 1), 256, 0, stream>>>(
        ctxb, Dc, wo, nullptr, nullptr, Dc,
        t1, bo + l * Dc, nullptr, nullptr, h,
        Bc * Sc, Dc, Dc);

    ln_k<<<Bc * Sc, 256, 0, stream>>>(t1, l1g + l * Dc, l1b + l * Dc, attn);

    // inter = gelu(attn @ Wi + bi) -> bf16
    gemm_k<false, EP_GELU><<<dim3(24, 32, 1), 256, 0, stream>>>(
        attn, Dc, wi, nullptr, nullptr, FFc,
        inter, bi + l * FFc, nullptr, nullptr, nullptr,
        Bc * Sc, FFc, Dc);

    // ff pre-LN = inter @ Wf + bf + attn
    gemm_k<true, EP_BIASRES><<<dim3(6, 32, 1), 256, 0, stream>>>(
        inter, FFc, wf, nullptr, nullptr, Dc,
        t1, bfp + l * Dc, nullptr, nullptr, attn,
        Bc * Sc, Dc, FFc);

    ln_k<<<Bc * Sc, 256, 0, stream>>>(t1, l2g + l * Dc, l2b + l * Dc, h);
  }

  pool_k<<<Bc, 256, 0, stream>>>(h, amask, out);
}

// Round 3
// 3949.275 us; speedup vs baseline: 2.1904x; 1.7004x over previous
//
#include <hip/hip_runtime.h>
#include <math.h>

// ---- model constants (fixed problem size) ----
#define Bc   8
#define Sc   512
#define Dc   768
#define Hc   12
#define DHc  64
#define FFc  3072
#define Lc   12

typedef float  floatx4 __attribute__((ext_vector_type(4)));
typedef short  shortx8 __attribute__((ext_vector_type(8)));
typedef short  shortx4 __attribute__((ext_vector_type(4)));
typedef __bf16 bf16x8  __attribute__((ext_vector_type(8)));

__device__ __forceinline__ short f2bf(float f) {
  union { float f; unsigned u; } x; x.f = f;
  unsigned r = x.u + 0x7fffu + ((x.u >> 16) & 1u);   // RNE
  return (short)(r >> 16);
}

// ---------------- weight transpose+convert: W f32 [K,N] -> Wt bf16 [N,K] ----
__global__ __launch_bounds__(256)
void wtr_k(const float* __restrict__ W, short* __restrict__ Wt, int K, int N) {
  __shared__ short sT[64 * 72];
  const int k0 = blockIdx.x * 64, n0 = blockIdx.y * 64;
  const long base = (long)blockIdx.z * K * N;
  W  += base;
  Wt += base;
  const int t = threadIdx.x;
  {
    int kr = t >> 4, nc = (t & 15) * 4;
    #pragma unroll
    for (int i = 0; i < 4; ++i) {
      int k = kr + i * 16;
      float4 v = *(const float4*)(W + (long)(k0 + k) * N + n0 + nc);
      shortx4 p; p.x = f2bf(v.x); p.y = f2bf(v.y); p.z = f2bf(v.z); p.w = f2bf(v.w);
      *(shortx4*)(sT + k * 72 + nc) = p;
    }
  }
  __syncthreads();
  {
    int nr = t >> 3, kc = (t & 7) * 8;
    #pragma unroll
    for (int i = 0; i < 2; ++i) {
      int n = nr + i * 32;
      shortx8 p;
      #pragma unroll
      for (int j = 0; j < 8; ++j) p[j] = sT[(kc + j) * 72 + n];
      *(shortx8*)(Wt + (long)(n0 + n) * K + k0 + kc) = p;
    }
  }
}

// ---------------- dense GEMM ----------------
// C[M,N] = A[M,K] @ B^T  (A bf16 [M][lda], B bf16 pre-transposed [N][lda]),
// tile 128x128x64, 256 threads = 4 waves 2x2, wave 64x64 via 4x4 MFMA 16x16x32.
#define LR 72   // LDS row stride (64 + 8 pad)

enum { EP_QKV, EP_ATOM, EP_GELU };

template<int EP>
__global__ __launch_bounds__(256, 2)
void gemm_k(const short* __restrict__ A, int lda,
            const short* __restrict__ B0, const short* __restrict__ B1,
            const short* __restrict__ B2,
            void* __restrict__ Cp,
            const float* __restrict__ bias0, const float* __restrict__ bias1,
            const float* __restrict__ bias2,
            int Nn, int Ksplit)
{
  __shared__ short sA[128 * LR];
  __shared__ short sB[128 * LR];

  const int tid = threadIdx.x;
  const int z   = blockIdx.z;
  const int m0  = blockIdx.y * 128;
  const int n0  = blockIdx.x * 128;

  const short* Bw;
  const float* bias;
  int kbase;
  if (EP == EP_QKV) {
    Bw   = (z == 0) ? B0 : (z == 1 ? B1 : B2);
    bias = (z == 0) ? bias0 : (z == 1 ? bias1 : bias2);
    kbase = 0;
  } else {
    Bw = B0; bias = bias0; kbase = z * Ksplit;
  }

  const short* Ag = A  + (long)m0 * lda + kbase;
  const short* Bg = Bw + (long)n0 * lda + kbase;

  floatx4 acc[4][4];
  #pragma unroll
  for (int i = 0; i < 4; ++i)
    #pragma unroll
    for (int j = 0; j < 4; ++j) acc[i][j] = (floatx4)0.f;

  const int wave = tid >> 6, lane = tid & 63;
  const int wm = (wave >> 1) * 64, wn = (wave & 1) * 64;
  const int quad = lane >> 4, r16 = lane & 15;
  const int sr = tid >> 3, scc = (tid & 7) * 8;   // staging row/col

  const int nkt = Ksplit / 64;
  for (int kt = 0; kt < nkt; ++kt) {
    const long ko_g = (long)kt * 64;
    #pragma unroll
    for (int i = 0; i < 4; ++i) {
      int r = sr + i * 32;
      *(shortx8*)(sA + r * LR + scc) = *(const shortx8*)(Ag + (long)r * lda + ko_g + scc);
    }
    #pragma unroll
    for (int i = 0; i < 4; ++i) {
      int r = sr + i * 32;
      *(shortx8*)(sB + r * LR + scc) = *(const shortx8*)(Bg + (long)r * lda + ko_g + scc);
    }
    __syncthreads();

    #pragma unroll
    for (int kc = 0; kc < 2; ++kc) {
      const int ko = kc * 32 + quad * 8;
      bf16x8 af[4], bv[4];
      #pragma unroll
      for (int mi = 0; mi < 4; ++mi)
        af[mi] = __builtin_bit_cast(bf16x8, *(const shortx8*)(sA + (wm + mi * 16 + r16) * LR + ko));
      #pragma unroll
      for (int ni = 0; ni < 4; ++ni)
        bv[ni] = __builtin_bit_cast(bf16x8, *(const shortx8*)(sB + (wn + ni * 16 + r16) * LR + ko));
      #pragma unroll
      for (int mi = 0; mi < 4; ++mi)
        #pragma unroll
        for (int ni = 0; ni < 4; ++ni)
          acc[mi][ni] = __builtin_amdgcn_mfma_f32_16x16x32_bf16(af[mi], bv[ni], acc[mi][ni], 0, 0, 0);
    }
    __syncthreads();
  }

  // ---- epilogue: C/D layout col=lane&15, row=quad*4+reg ----
  #pragma unroll
  for (int mi = 0; mi < 4; ++mi) {
    #pragma unroll
    for (int ni = 0; ni < 4; ++ni) {
      #pragma unroll
      for (int r = 0; r < 4; ++r) {
        int mm = m0 + wm + mi * 16 + quad * 4 + r;
        int nn = n0 + wn + ni * 16 + r16;
        float v = acc[mi][ni][r];
        if (EP == EP_QKV) {
          v += bias[nn];
          int b = mm >> 9, s = mm & 511;
          int hh = nn >> 6, dd = nn & 63;
          ((short*)Cp)[((((long)z * Bc + b) * Hc + hh) * Sc + s) * DHc + dd] = f2bf(v);
        } else if (EP == EP_ATOM) {
          atomicAdd(&((float*)Cp)[(long)mm * Nn + nn], v);
        } else if (EP == EP_GELU) {
          v += bias[nn];
          float g = 0.5f * v * (1.f + erff(v * 0.70710678118654752f));
          ((short*)Cp)[(long)mm * Nn + nn] = f2bf(g);
        }
      }
    }
  }
}

// ---------------- fused flash attention (unchanged from R2) ----------------
#define HDL ((long)Bc * Hc * Sc * DHc)

__global__ __launch_bounds__(256, 2)
void attn_k(const short* __restrict__ qkv, const int* __restrict__ msk,
            short* __restrict__ ctx)
{
  __shared__ short sQ[128 * 72];
  __shared__ short sK[64 * 72];
  __shared__ short sV[64 * 72];   // transposed [dh][kn], rotated
  __shared__ short sP[128 * 72];

  const int tid = threadIdx.x;
  const int qt = blockIdx.x, bh = blockIdx.y;
  const int b = bh / Hc, hh = bh % Hc;
  const int wave = tid >> 6, lane = tid & 63;
  const int quad = lane >> 4, r16 = lane & 15;

  const short* Qg = qkv + ((long)bh * Sc + qt * 128) * DHc;
  const short* Kg = qkv + HDL + (long)bh * Sc * DHc;
  const short* Vg = qkv + 2 * HDL + (long)bh * Sc * DHc;

  #pragma unroll
  for (int i = 0; i < 4; ++i) {
    int id = tid + i * 256;
    int r = id >> 3, c = (id & 7) * 8;
    *(shortx8*)(sQ + r * 72 + c) = *(const shortx8*)(Qg + r * 64 + c);
  }

  floatx4 o[2][4];
  float m_old[2][4], l[2][4];
  #pragma unroll
  for (int mi = 0; mi < 2; ++mi) {
    #pragma unroll
    for (int nj = 0; nj < 4; ++nj) o[mi][nj] = (floatx4)0.f;
    #pragma unroll
    for (int r = 0; r < 4; ++r) { m_old[mi][r] = -3.0e38f; l[mi][r] = 0.f; }
  }

  for (int kt = 0; kt < 8; ++kt) {
    __syncthreads();
    #pragma unroll
    for (int i = 0; i < 2; ++i) {
      int id = tid + i * 256;
      int r = id >> 3, c = (id & 7) * 8;
      *(shortx8*)(sK + r * 72 + c) = *(const shortx8*)(Kg + (kt * 64 + r) * 64 + c);
    }
    #pragma unroll
    for (int i = 0; i < 2; ++i) {
      int id = tid + i * 256;
      int r = id >> 3, c8 = id & 7;
      shortx8 v = *(const shortx8*)(Vg + (kt * 64 + r) * 64 + c8 * 8);
      #pragma unroll
      for (int j = 0; j < 8; ++j) {
        int kn2 = (r + 8 * ((j + c8) & 7)) & 63;
        sV[(c8 * 8 + j) * 72 + kn2] = v[j];
      }
    }
    __syncthreads();

    floatx4 s[2][4];
    #pragma unroll
    for (int mi = 0; mi < 2; ++mi)
      #pragma unroll
      for (int ni = 0; ni < 4; ++ni) s[mi][ni] = (floatx4)0.f;
    #pragma unroll
    for (int kc = 0; kc < 2; ++kc) {
      const int ko = kc * 32 + quad * 8;
      bf16x8 aq[2], bk[4];
      #pragma unroll
      for (int mi = 0; mi < 2; ++mi)
        aq[mi] = __builtin_bit_cast(bf16x8, *(const shortx8*)(sQ + (wave * 32 + mi * 16 + r16) * 72 + ko));
      #pragma unroll
      for (int ni = 0; ni < 4; ++ni)
        bk[ni] = __builtin_bit_cast(bf16x8, *(const shortx8*)(sK + (ni * 16 + r16) * 72 + ko));
      #pragma unroll
      for (int mi = 0; mi < 2; ++mi)
        #pragma unroll
        for (int ni = 0; ni < 4; ++ni)
          s[mi][ni] = __builtin_amdgcn_mfma_f32_16x16x32_bf16(aq[mi], bk[ni], s[mi][ni], 0, 0, 0);
    }

    float mv[4];
    #pragma unroll
    for (int ni = 0; ni < 4; ++ni)
      mv[ni] = (float)msk[b * Sc + kt * 64 + ni * 16 + r16];

    #pragma unroll
    for (int mi = 0; mi < 2; ++mi) {
      #pragma unroll
      for (int r = 0; r < 4; ++r) {
        float mx = fmaxf(fmaxf(s[mi][0][r], s[mi][1][r]), fmaxf(s[mi][2][r], s[mi][3][r]));
        mx *= 0.125f;
        #pragma unroll
        for (int off = 1; off <= 8; off <<= 1) mx = fmaxf(mx, __shfl_xor(mx, off));
        float mn = fmaxf(m_old[mi][r], mx);
        float al = __expf(m_old[mi][r] - mn);
        m_old[mi][r] = mn;
        float rs = 0.f;
        #pragma unroll
        for (int ni = 0; ni < 4; ++ni) {
          float p = __expf(fmaf(s[mi][ni][r], 0.125f, -mn)) * mv[ni];
          s[mi][ni][r] = p;
          rs += p;
        }
        #pragma unroll
        for (int off = 1; off <= 8; off <<= 1) rs += __shfl_xor(rs, off);
        l[mi][r] = l[mi][r] * al + rs;
        #pragma unroll
        for (int nj = 0; nj < 4; ++nj) o[mi][nj][r] *= al;
        int row = wave * 32 + mi * 16 + quad * 4 + r;
        #pragma unroll
        for (int ni = 0; ni < 4; ++ni)
          sP[row * 72 + ni * 16 + r16] = f2bf(s[mi][ni][r]);
      }
    }
    __syncthreads();

    #pragma unroll
    for (int kc = 0; kc < 2; ++kc) {
      const int ko = kc * 32 + quad * 8;
      bf16x8 ap[2], bv[4];
      #pragma unroll
      for (int mi = 0; mi < 2; ++mi)
        ap[mi] = __builtin_bit_cast(bf16x8, *(const shortx8*)(sP + (wave * 32 + mi * 16 + r16) * 72 + ko));
      #pragma unroll
      for (int nj = 0; nj < 4; ++nj) {
        int dh = nj * 16 + r16;
        int f = (dh + (dh >> 3)) & 7;
        int base = (ko + 8 * f) & 63;
        bv[nj] = __builtin_bit_cast(bf16x8, *(const shortx8*)(sV + dh * 72 + base));
      }
      #pragma unroll
      for (int mi = 0; mi < 2; ++mi)
        #pragma unroll
        for (int nj = 0; nj < 4; ++nj)
          o[mi][nj] = __builtin_amdgcn_mfma_f32_16x16x32_bf16(ap[mi], bv[nj], o[mi][nj], 0, 0, 0);
    }
  }

  #pragma unroll
  for (int mi = 0; mi < 2; ++mi) {
    #pragma unroll
    for (int r = 0; r < 4; ++r) {
      float inv = 1.f / fmaxf(l[mi][r], 1e-20f);
      int row = qt * 128 + wave * 32 + mi * 16 + quad * 4 + r;
      #pragma unroll
      for (int nj = 0; nj < 4; ++nj) {
        int col = hh * 64 + nj * 16 + r16;
        ctx[((long)b * Sc + row) * Dc + col] = f2bf(o[mi][nj][r] * inv);
      }
    }
  }
}

// ---------------- reductions / LN ----------------
__device__ __forceinline__ void block_red2(float& s, float& ss) {
  #pragma unroll
  for (int off = 32; off; off >>= 1) {
    s  += __shfl_xor(s, off);
    ss += __shfl_xor(ss, off);
  }
  __shared__ float rs[4], rss[4];
  int wave = threadIdx.x >> 6, lane = threadIdx.x & 63;
  __syncthreads();
  if (lane == 0) { rs[wave] = s; rss[wave] = ss; }
  __syncthreads();
  s  = rs[0] + rs[1] + rs[2] + rs[3];
  ss = rss[0] + rss[1] + rss[2] + rss[3];
}

__device__ __forceinline__ void ln3_dual(float a0, float a1, float a2,
                                         const float* __restrict__ g,
                                         const float* __restrict__ bb,
                                         float* __restrict__ outf,
                                         short* __restrict__ outb, int tid) {
  float s = a0 + a1 + a2;
  float ss = a0 * a0 + a1 * a1 + a2 * a2;
  block_red2(s, ss);
  float mu  = s * (1.f / 768.f);
  float var = ss * (1.f / 768.f) - mu * mu;
  float rstd = rsqrtf(var + 1e-12f);
  float y0 = (a0 - mu) * rstd * g[tid]       + bb[tid];
  float y1 = (a1 - mu) * rstd * g[tid + 256] + bb[tid + 256];
  float y2 = (a2 - mu) * rstd * g[tid + 512] + bb[tid + 512];
  outf[tid] = y0; outf[tid + 256] = y1; outf[tid + 512] = y2;
  outb[tid] = f2bf(y0); outb[tid + 256] = f2bf(y1); outb[tid + 512] = f2bf(y2);
}

// reduce (from atomically-accumulated t1) + bias + residual + LN; re-zeros t1
__global__ __launch_bounds__(256)
void red_ln_k(float* __restrict__ t1, const float* __restrict__ res,
              const float* __restrict__ bias,
              const float* __restrict__ g, const float* __restrict__ bb,
              float* __restrict__ outf, short* __restrict__ outb) {
  long base = (long)blockIdx.x * Dc;
  int tid = threadIdx.x;
  float a0 = t1[base + tid]       + bias[tid]       + res[base + tid];
  float a1 = t1[base + tid + 256] + bias[tid + 256] + res[base + tid + 256];
  float a2 = t1[base + tid + 512] + bias[tid + 512] + res[base + tid + 512];
  t1[base + tid] = 0.f; t1[base + tid + 256] = 0.f; t1[base + tid + 512] = 0.f;
  ln3_dual(a0, a1, a2, g, bb, outf + base, outb + base, tid);
}

__global__ __launch_bounds__(256)
void embed_k(const int* __restrict__ ids, const float* __restrict__ we,
             const float* __restrict__ pe, const float* __restrict__ te,
             const float* __restrict__ g, const float* __restrict__ bb,
             float* __restrict__ y, short* __restrict__ yb) {
  int row = blockIdx.x, tid = threadIdx.x;
  int s = row & 511;
  long wo = (long)ids[row] * Dc;
  long po = (long)s * Dc;
  float a0 = we[wo + tid]       + pe[po + tid]       + te[tid];
  float a1 = we[wo + tid + 256] + pe[po + tid + 256] + te[tid + 256];
  float a2 = we[wo + tid + 512] + pe[po + tid + 512] + te[tid + 512];
  ln3_dual(a0, a1, a2, g, bb, y + (long)row * Dc, yb + (long)row * Dc, tid);
}

// mean-pool over S with mask, then L2-normalize; one block per batch
__global__ __launch_bounds__(256)
void pool_k(const float* __restrict__ h, const int* __restrict__ msk,
            float* __restrict__ out) {
  int b = blockIdx.x, tid = threadIdx.x;
  float cnt = 0.f, d0 = 0.f;
  for (int s = tid; s < Sc; s += 256) cnt += (float)msk[b * Sc + s];
  block_red2(cnt, d0);
  float a0 = 0.f, a1 = 0.f, a2 = 0.f;
  const float* hb = h + (long)b * Sc * Dc;
  for (int s = 0; s < Sc; ++s) {
    float mk = (float)msk[b * Sc + s];
    if (mk != 0.f) {
      const float* hr = hb + (long)s * Dc;
      a0 += hr[tid] * mk; a1 += hr[tid + 256] * mk; a2 += hr[tid + 512] * mk;
    }
  }
  float dn = 1.f / fmaxf(cnt, 1e-6f);
  a0 *= dn; a1 *= dn; a2 *= dn;
  float ssq = a0 * a0 + a1 * a1 + a2 * a2, d1 = 0.f;
  block_red2(ssq, d1);
  float rn = 1.f / fmaxf(sqrtf(ssq), 1e-12f);
  out[b * Dc + tid]       = a0 * rn;
  out[b * Dc + tid + 256] = a1 * rn;
  out[b * Dc + tid + 512] = a2 * rn;
}

// ---------------- launcher ----------------
extern "C" void kernel_launch(void* const* d_in, const int* in_sizes, int n_in,
                              void* d_out, int out_size, void* d_ws, size_t ws_size,
                              hipStream_t stream)
{
  const int*   ids   = (const int*)d_in[0];
  const int*   amask = (const int*)d_in[1];
  const float* we    = (const float*)d_in[2];
  const float* pe    = (const float*)d_in[3];
  const float* te    = (const float*)d_in[4];
  const float* elg   = (const float*)d_in[5];
  const float* elb   = (const float*)d_in[6];
  const float* Wq    = (const float*)d_in[7];
  const float* bq    = (const float*)d_in[8];
  const float* Wk    = (const float*)d_in[9];
  const float* bk    = (const float*)d_in[10];
  const float* Wv    = (const float*)d_in[11];
  const float* bv    = (const float*)d_in[12];
  const float* Wo    = (const float*)d_in[13];
  const float* bo    = (const float*)d_in[14];
  const float* l1g   = (const float*)d_in[15];
  const float* l1b   = (const float*)d_in[16];
  const float* Wi    = (const float*)d_in[17];
  const float* bi    = (const float*)d_in[18];
  const float* Wf    = (const float*)d_in[19];
  const float* bfp   = (const float*)d_in[20];
  const float* l2g   = (const float*)d_in[21];
  const float* l2b   = (const float*)d_in[22];
  float* out = (float*)d_out;

  const long HD = (long)Bc * Sc * Dc;        // 3,145,728
  const long DD = (long)Dc * Dc;             // 589,824
  const long DF = (long)Dc * FFc;            // 2,359,296

  // --- workspace layout ---
  short* wsS = (short*)d_ws;
  short* WqT = wsS;                 // [L][768][768]
  short* WkT = WqT + Lc * DD;
  short* WvT = WkT + Lc * DD;
  short* WoT = WvT + Lc * DD;
  short* WiT = WoT + Lc * DD;       // [L][3072][768]
  short* WfT = WiT + Lc * DF;       // [L][768][3072]
  long wEnd = 4 * Lc * DD + 2 * Lc * DF;       // shorts (= 84,934,656)

  float* wsF  = (float*)d_ws;
  long fBase  = wEnd / 2;                       // float index (wEnd even)
  float* h    = wsF + fBase;                    // HD f32 residual
  float* attn = h + HD;
  float* t1   = attn + HD;                      // split-K accumulator
  long sBase  = 2 * (fBase + 3 * HD);           // short index
  short* hb    = wsS + sBase;                   // HD bf16
  short* attnb = hb + HD;
  short* qkvb  = attnb + HD;                    // [3][B,H,S,DH]
  short* ctxb  = qkvb + 3 * HD;
  short* inter = ctxb + HD;                     // [B,S,FF]

  // --- once per call: zero the atomic accumulator, transpose weights ---
  hipMemsetAsync(t1, 0, HD * sizeof(float), stream);
  wtr_k<<<dim3(Dc / 64, Dc / 64, Lc), 256, 0, stream>>>(Wq, WqT, Dc, Dc);
  wtr_k<<<dim3(Dc / 64, Dc / 64, Lc), 256, 0, stream>>>(Wk, WkT, Dc, Dc);
  wtr_k<<<dim3(Dc / 64, Dc / 64, Lc), 256, 0, stream>>>(Wv, WvT, Dc, Dc);
  wtr_k<<<dim3(Dc / 64, Dc / 64, Lc), 256, 0, stream>>>(Wo, WoT, Dc, Dc);
  wtr_k<<<dim3(Dc / 64, FFc / 64, Lc), 256, 0, stream>>>(Wi, WiT, Dc, FFc);
  wtr_k<<<dim3(FFc / 64, Dc / 64, Lc), 256, 0, stream>>>(Wf, WfT, FFc, Dc);

  embed_k<<<Bc * Sc, 256, 0, stream>>>(ids, we, pe, te, elg, elb, h, hb);

  for (int l = 0; l < Lc; ++l) {
    // QKV: z selects W/bias; out bf16 [3][B,H,S,DH]
    gemm_k<EP_QKV><<<dim3(6, 32, 3), 256, 0, stream>>>(
        hb, Dc, WqT + l * DD, WkT + l * DD, WvT + l * DD, qkvb,
        bq + l * Dc, bk + l * Dc, bv + l * Dc, Dc, Dc);

    // fused flash attention -> ctx bf16 [B,S,D]
    attn_k<<<dim3(4, 96), 256, 0, stream>>>(qkvb, amask, ctxb);

    // ctx @ Wo, split-K=2, atomic accumulate into t1
    gemm_k<EP_ATOM><<<dim3(6, 32, 2), 256, 0, stream>>>(
        ctxb, Dc, WoT + l * DD, nullptr, nullptr, t1,
        nullptr, nullptr, nullptr, Dc, Dc / 2);

    // attn = LN(t1 + bo + h)  (re-zeros t1)
    red_ln_k<<<Bc * Sc, 256, 0, stream>>>(t1, h, bo + l * Dc,
                                          l1g + l * Dc, l1b + l * Dc, attn, attnb);

    // inter = gelu(attn @ Wi + bi) -> bf16
    gemm_k<EP_GELU><<<dim3(24, 32, 1), 256, 0, stream>>>(
        attnb, Dc, WiT + l * DF, nullptr, nullptr, inter,
        bi + l * FFc, nullptr, nullptr, FFc, Dc);

    // inter @ Wf, split-K=4, atomic accumulate into t1
    gemm_k<EP_ATOM><<<dim3(6, 32, 4), 256, 0, stream>>>(
        inter, FFc, WfT + l * DF, nullptr, nullptr, t1,
        nullptr, nullptr, nullptr, Dc, FFc / 4);

    // h = LN(t1 + bf + attn)  (re-zeros t1)
    red_ln_k<<<Bc * Sc, 256, 0, stream>>>(t1, attn, bfp + l * Dc,
                                          l2g + l * Dc, l2b + l * Dc, h, hb);
  }

  pool_k<<<Bc, 256, 0, stream>>>(h, amask, out);
}